// Round 9
// baseline (268.450 us; speedup 1.0000x reference)
//
#include <hip/hip_runtime.h>

// TALayer: deformable 1D conv, fixed integer taps d[j] ∈ {-17,-16,-15,-1,0,1,15,16,17}
// out[b,o,t] = sum_{c,j} W[o,c,j] * x[b,c,t+d[j]] (zero-pad OOB) + bias[o]
// B=8, C=O=64, T=65536. bf16 MFMA GEMM: C[64, B*T] = W[64,576] * Xg[576, B*T].
// R7: (256,3) + K-loop 1-chunk pipeline + XCD swizzle: 197->133us (occ 26%).
// R8 FAILED: persistent 4-tile pipeline spilled (FETCH 400MB). Reverted.
// R9: NT 128, 4 waves, nt=2, (256,4): 133->108us. occ 35%, MfmaUtil 14.5%,
//     WRITE exactly 1.0x output, FETCH 66MB. Still latency-bound at 23% HBM.
//     Per chunk 4 W2 L2-loads (~200cyc, 1-deep) covered by only 8 MFMA.
// R10: 128-thread blocks (2 waves), each wave owns 64 t (nt=4), NT=128.
//     (a) 16 MFMA/wave per chunk covers W2 L2 latency; (b) W2 traffic per
//     block halves; (c) LDS 22.8KB + launch_bounds(128,3) -> 12 waves/CU.
// R11/R12: broker infra failures (never reached GPU).
// R13: Round-8 run crashed (core dump) on a demonstrably degraded container
//     (npz push 2532s vs ~12s healthy; pytest died at 7.2s). Double audit of
//     all address paths found no fault. Final resubmit; fallback = R9 base.

typedef short bf16x8 __attribute__((ext_vector_type(8)));   // 8 bf16 (4 VGPRs)
typedef short bf16x4 __attribute__((ext_vector_type(4)));   // 4 bf16 (8 B, ds_read_b64)
typedef float f32x4  __attribute__((ext_vector_type(4)));   // MFMA accumulator / 16B vec

#define T_LEN   65536
#define NT      128           // t-tile per block
#define ROWS    168           // staged rows: global t in [t0-20, t0+148)
#define PITCH   68            // shorts per LDS row (136 B)
#define LOFF    20            // x[t] -> LDS row (t - t0 + 20)
#define NCHUNK  18            // K = 576 = 18 * 32
#define OPITCH  132           // floats per epilogue LDS row (132 = 4*33, 16B-aligned rows)
#define XS_BYTES (ROWS * PITCH * 2)     // 22,848 B
#define SMEM_BYTES XS_BYTES             // os (16,896 B) aliased inside

__device__ __forceinline__ short f2bf(float f) {
    union { float f; unsigned u; } v; v.f = f;
    unsigned u = v.u;
    u += 0x7fffu + ((u >> 16) & 1u);   // round-to-nearest-even
    return (short)(u >> 16);
}

// Weight -> MFMA A-fragment order (bf16), layout [ch][mt][lane][8]:
// W2[((ch*4 + mt)*64 + lane)*8 + i] = bf16(W[o = mt*16 + (lane&15)][kk = ch*32 + (lane>>4)*8 + i])
// kk = j*64 + c -> j = kk>>6, c = kk&63;  W strides [o][c][j] = (576, 9, 1).
__global__ void prep_w_kernel(const float* __restrict__ w, short* __restrict__ W2) {
    int idx = blockIdx.x * 256 + threadIdx.x;       // 0 .. 4607
    if (idx >= 4 * NCHUNK * 64) return;
    int lane = idx & 63;
    int g    = idx >> 6;            // ch*4 + mt
    int ch   = g >> 2;
    int mt   = g & 3;
    int o    = mt * 16 + (lane & 15);
    bf16x8 v;
#pragma unroll
    for (int i = 0; i < 8; ++i) {
        int kk = ch * 32 + (lane >> 4) * 8 + i;
        int j = kk >> 6, c = kk & 63;
        v[i] = f2bf(w[o * 576 + c * 9 + j]);
    }
    *(bf16x8*)(W2 + (size_t)idx * 8) = v;
}

__global__ __launch_bounds__(128, 3)
void ta_main_kernel(const float* __restrict__ x, const short* __restrict__ W2,
                    const float* __restrict__ bias, float* __restrict__ out) {
    __shared__ __align__(16) char smem[SMEM_BYTES];
    short* xs = (short*)smem;                       // staging: [tt][c] bf16, pitch 68
    float* os = (float*)smem;                       // epilogue: [o_local][t] f32, pitch 132

    const int tid  = threadIdx.x;                   // 0..127
    const int wv   = tid >> 6;                      // wave -> t-half (64 t each)
    const int lane = tid & 63;
    const int l15  = lane & 15;
    const int quad = lane >> 4;
    const int b    = blockIdx.y;
    // XCD swizzle: gridDim.x = 512 ≡ 0 mod 8 -> bijective. XCD k owns 64
    // consecutive bx (8192 consecutive t): halo L2 reuse + contiguous writes.
    const int bxd  = blockIdx.x;                    // 0..511
    const int bx   = (bxd & 7) * 64 + (bxd >> 3);
    const int t0   = bx * NT;

    // ---- stage x tile: batched float4 loads, transpose to [tt][c] bf16 in LDS ----
    // 128 threads: c = tid>>1 (64 channels), q = tid&1, f = q + 2i, i < 21 (42 f4/c)
    const int c = tid >> 1;
    const int q = tid & 1;
    const float* xrow = x + (((size_t)(b * 64 + c)) << 16);
    const int tbase = t0 - LOFF;
    const bool interior = (t0 >= LOFF) && (t0 + (ROWS - LOFF) <= T_LEN);

    if (interior) {
        // issue all 21 independent f32x4 loads first, then convert + ds_write
        f32x4 v[21];
#pragma unroll
        for (int i = 0; i < 21; ++i) {
            const int f = q + 2 * i;                // 0..41, exact cover
            v[i] = *(const f32x4*)(xrow + tbase + 4 * f);
        }
#pragma unroll
        for (int i = 0; i < 21; ++i) {
            const int f = q + 2 * i;
            const int tt = 4 * f;
            xs[(tt + 0) * PITCH + c] = f2bf(v[i][0]);
            xs[(tt + 1) * PITCH + c] = f2bf(v[i][1]);
            xs[(tt + 2) * PITCH + c] = f2bf(v[i][2]);
            xs[(tt + 3) * PITCH + c] = f2bf(v[i][3]);
        }
    } else {
        // boundary blocks (2 of 512 along x): scalar clamped path
#pragma unroll
        for (int i = 0; i < 21; ++i) {
            const int f = q + 2 * i;
            const int tt = 4 * f;
            const int tg = tbase + tt;
            f32x4 v;
            v[0] = ((unsigned)(tg + 0) < (unsigned)T_LEN) ? xrow[tg + 0] : 0.f;
            v[1] = ((unsigned)(tg + 1) < (unsigned)T_LEN) ? xrow[tg + 1] : 0.f;
            v[2] = ((unsigned)(tg + 2) < (unsigned)T_LEN) ? xrow[tg + 2] : 0.f;
            v[3] = ((unsigned)(tg + 3) < (unsigned)T_LEN) ? xrow[tg + 3] : 0.f;
            xs[(tt + 0) * PITCH + c] = f2bf(v[0]);
            xs[(tt + 1) * PITCH + c] = f2bf(v[1]);
            xs[(tt + 2) * PITCH + c] = f2bf(v[2]);
            xs[(tt + 3) * PITCH + c] = f2bf(v[3]);
        }
    }
    __syncthreads();

    // ---- K loop: 18 chunks of 32 (chunk ch: tap j = ch>>1, c-half h = ch&1) ----
    // 1-chunk software pipeline: prefetch (a,b) of chunk ch+1 before MFMAs of ch.
    // nt=4: per chunk 4 W2 L2-loads feed 16 MFMAs -> latency covered.
    int bbase[4];
#pragma unroll
    for (int nt = 0; nt < 4; ++nt) {
        const int tl = wv * 64 + nt * 16 + l15;
        bbase[nt] = (tl + 3) * PITCH + quad * 8;    // shorts; +3 so roff >= 0
    }
    const short* w2p = W2 + (size_t)lane * 8;

    f32x4 acc[4][4] = {};                           // [mt][nt]

    const int dtab[9] = {-17, -16, -15, -1, 0, 1, 15, 16, 17};

    bf16x8 a_cur[4], b_cur[4], a_nxt[4], b_nxt[4];

    // prologue: load chunk 0
    {
        const int roff0 = (dtab[0] + 17) * PITCH + 0;
#pragma unroll
        for (int mt = 0; mt < 4; ++mt)
            a_cur[mt] = *(const bf16x8*)(w2p + (size_t)(0 * 4 + mt) * 512);
#pragma unroll
        for (int nt = 0; nt < 4; ++nt) {
            union { bf16x8 v8; bf16x4 v4[2]; } u;
            u.v4[0] = *(const bf16x4*)(xs + bbase[nt] + roff0);
            u.v4[1] = *(const bf16x4*)(xs + bbase[nt] + roff0 + 4);
            b_cur[nt] = u.v8;
        }
    }

#pragma unroll
    for (int ch = 0; ch < NCHUNK; ++ch) {
        if (ch < NCHUNK - 1) {
            const int chn = ch + 1;
            const int jn = chn >> 1, hn = chn & 1;
            const int roffn = (dtab[jn] + 17) * PITCH + hn * 32;   // compile-time
#pragma unroll
            for (int mt = 0; mt < 4; ++mt)
                a_nxt[mt] = *(const bf16x8*)(w2p + (size_t)(chn * 4 + mt) * 512);
#pragma unroll
            for (int nt = 0; nt < 4; ++nt) {
                union { bf16x8 v8; bf16x4 v4[2]; } u;
                u.v4[0] = *(const bf16x4*)(xs + bbase[nt] + roffn);
                u.v4[1] = *(const bf16x4*)(xs + bbase[nt] + roffn + 4);
                b_nxt[nt] = u.v8;
            }
        }
#pragma unroll
        for (int mt = 0; mt < 4; ++mt)
#pragma unroll
            for (int nt = 0; nt < 4; ++nt)
                acc[mt][nt] = __builtin_amdgcn_mfma_f32_16x16x32_bf16(a_cur[mt], b_cur[nt], acc[mt][nt], 0, 0, 0);
        if (ch < NCHUNK - 1) {
#pragma unroll
            for (int mt = 0; mt < 4; ++mt) { a_cur[mt] = a_nxt[mt]; b_cur[mt] = b_nxt[mt]; }
        }
    }

    // ---- epilogue: round-trip through LDS so each wave writes contiguous lines ----
    // C/D layout: row(m) = quad*4 + r, col(n) = lane&15
    // Two passes (o in [0,32) then [32,64)), each: acc -> LDS [o_local][t] -> stores.
    const size_t outb = ((size_t)(b * 64)) << 16;
#pragma unroll
    for (int p = 0; p < 2; ++p) {
        __syncthreads();                            // xs reads (p=0) / os reads (p=1) done
#pragma unroll
        for (int mtl = 0; mtl < 2; ++mtl) {
            const int mt = 2 * p + mtl;
#pragma unroll
            for (int r = 0; r < 4; ++r) {
                const int ol = mtl * 16 + quad * 4 + r;           // 0..31
                const float bv = bias[mt * 16 + quad * 4 + r];
#pragma unroll
                for (int nt = 0; nt < 4; ++nt) {
                    const int t = wv * 64 + nt * 16 + l15;
                    os[ol * OPITCH + t] = acc[mt][nt][r] + bv;    // 2-way bank: free
                }
            }
        }
        __syncthreads();
        // read back + store: item = [o_local][f4], 32*32 items; 512B contiguous per row
#pragma unroll
        for (int i = 0; i < 8; ++i) {
            const int item = tid + 128 * i;         // 0..1023
            const int ol = item >> 5;               // 0..31
            const int f4 = item & 31;               // 0..31
            const f32x4 v = *(const f32x4*)(os + ol * OPITCH + 4 * f4);
            const int o = p * 32 + ol;
            *(f32x4*)(out + outb + (((size_t)o) << 16) + t0 + 4 * f4) = v;
        }
    }
}

extern "C" void kernel_launch(void* const* d_in, const int* in_sizes, int n_in,
                              void* d_out, int out_size, void* d_ws, size_t ws_size,
                              hipStream_t stream) {
    const float* x    = (const float*)d_in[0];
    const float* w    = (const float*)d_in[1];
    const float* bias = (const float*)d_in[2];
    float* out = (float*)d_out;
    short* W2  = (short*)d_ws;                      // 4*18*64*8*2 = 73,728 B

    hipLaunchKernelGGL(prep_w_kernel, dim3(18), dim3(256), 0, stream, w, W2);
    hipLaunchKernelGGL(ta_main_kernel, dim3(T_LEN / NT, 8), dim3(128), 0, stream,
                       x, W2, bias, out);
}